// Round 2
// baseline (1590.602 us; speedup 1.0000x reference)
//
#include <hip/hip_runtime.h>

#define NH 256
#define KN 16
#define STR 264     // padded row stride (floats) for 16x256 feature buffers
#define NGRAPH 512

typedef float float4v __attribute__((ext_vector_type(4)));

__device__ __forceinline__ float4v ld4(const float* p){ return *(const float4v*)p; }
__device__ __forceinline__ void st4(float* p, float4v v){ *(float4v*)p = v; }

// C[16][NH] (LDS, stride STR) = act(A[16][NH] @ Bg[NH][NH] + bias)
// split-K-4 across lane quads; 8x8 register tiles; quad butterfly reduce.
template<bool RELU, bool HASBIAS>
__device__ __forceinline__ void small_gemm(const float* __restrict__ A,
                                           const float* __restrict__ Bg,
                                           const float* __restrict__ bias,
                                           float* __restrict__ C,
                                           float* __restrict__ BtS,   // >= 4112 floats LDS scratch
                                           float* __restrict__ AtS,   // >= 256 floats LDS scratch
                                           int tid)
{
    const int s  = tid & 3;           // K-slice
    const int cg = (tid >> 2) & 31;   // 8 cols each
    const int rg = (tid >> 7) & 1;    // 8 rows each
    float acc[8][8];
#pragma unroll
    for (int m = 0; m < 8; ++m)
#pragma unroll
        for (int c = 0; c < 8; ++c) acc[m][c] = 0.f;

    for (int step = 0; step < 16; ++step) {
        const int ks = step * 4;
        __syncthreads();
        // stage B tile: rows {s*64+ks+kt : s in 0..3, kt in 0..3} -> BtS (s-stride 1028 for bank spread)
#pragma unroll
        for (int vi = 0; vi < 4; ++vi) {
            int v = tid * 4 + vi;
            int ss = v >> 8, kt = (v >> 6) & 3, c = (v & 63) * 4;
            st4(BtS + ss * 1028 + kt * 256 + c,
                ld4(Bg + (ss * 64 + ks + kt) * NH + c));
        }
        // stage A^T tile: AtS[kt][s][r]
        {
            int kt = tid >> 6, ss = (tid >> 4) & 3, r = tid & 15;
            AtS[kt * 64 + ss * 16 + r] = A[r * STR + ss * 64 + ks + kt];
        }
        __syncthreads();
#pragma unroll
        for (int kt = 0; kt < 4; ++kt) {
            const float* ap = AtS + kt * 64 + s * 16 + rg * 8;
            const float* bp = BtS + s * 1028 + kt * 256 + cg * 8;
            float4v a0 = ld4(ap), a1 = ld4(ap + 4);
            float4v b0 = ld4(bp), b1 = ld4(bp + 4);
            float a[8] = {a0[0],a0[1],a0[2],a0[3],a1[0],a1[1],a1[2],a1[3]};
            float b[8] = {b0[0],b0[1],b0[2],b0[3],b1[0],b1[1],b1[2],b1[3]};
#pragma unroll
            for (int m = 0; m < 8; ++m)
#pragma unroll
                for (int c = 0; c < 8; ++c)
                    acc[m][c] = fmaf(a[m], b[c], acc[m][c]);
        }
    }
    // butterfly-reduce over the 4 K-slices (quad lanes)
#pragma unroll
    for (int m = 0; m < 8; ++m)
#pragma unroll
        for (int c = 0; c < 8; ++c) {
            float v = acc[m][c];
            v += __shfl_xor(v, 1);
            v += __shfl_xor(v, 2);
            acc[m][c] = v;
        }
    if (s == 0) {   // one lane per quad writes the 8x8 block (static acc indexing)
        const int c0 = cg * 8;
#pragma unroll
        for (int m = 0; m < 8; ++m) {
            const int r = rg * 8 + m;
            float o[8];
#pragma unroll
            for (int c = 0; c < 8; ++c) {
                float v = acc[m][c];
                if (HASBIAS) v += bias[c0 + c];
                if (RELU)    v = fmaxf(v, 0.f);
                o[c] = v;
            }
            st4(C + r * STR + c0,     (float4v){o[0], o[1], o[2], o[3]});
            st4(C + r * STR + c0 + 4, (float4v){o[4], o[5], o[6], o[7]});
        }
    }
}

__global__ __launch_bounds__(256, 2)
void fcgn_kernel(const float* __restrict__ towers, const float* __restrict__ We,
                 const float* __restrict__ be,  const float* __restrict__ Wm1,
                 const float* __restrict__ bm1, const float* __restrict__ Wm2,
                 const float* __restrict__ bm2, const float* __restrict__ Wu1,
                 const float* __restrict__ bu1, const float* __restrict__ Wu2,
                 const float* __restrict__ bu2, const float* __restrict__ Wo1,
                 const float* __restrict__ bo1, const float* __restrict__ Wo2,
                 const float* __restrict__ bo2, const int* __restrict__ kPtr,
                 float* __restrict__ out)
{
    __shared__ alignas(16) float SB[4][KN * STR];   // h / p / q / e (roles rotate)
    __shared__ alignas(16) float BTB[8 * 256];      // Wm2 k-tile
    __shared__ alignas(16) float ATB[8 * 128];      // relu(pre)^T tile (also small-gemm AtS)
    __shared__ float TW[224];
    __shared__ float LG[16];

    const int g = blockIdx.x;
    const int tid = threadIdx.x;

    if (tid < 224) TW[tid] = towers[g * 224 + tid];
    __syncthreads();

    // ---- encoder: h = towers @ We + be ----
    {
        const int r = tid >> 4, u = tid & 15;
        for (int cc = 0; cc < 16; ++cc) {
            const int c = cc * 16 + u;
            float sum = be[c];
#pragma unroll
            for (int f = 0; f < 14; ++f)
                sum = fmaf(TW[r * 14 + f], We[f * NH + c], sum);
            SB[0][r * STR + c] = sum;
        }
    }

    float* bH = SB[0]; float* bP = SB[1]; float* bQ = SB[2]; float* bE = SB[3];
    int kk = kPtr[0];
    if (kk < 0) kk = 0;
    if (kk > 8) kk = 8;      // defensive clamp: a garbage k must not hang the GPU

    for (int rnd = 0; rnd < kk; ++rnd) {
        // p = h @ Wm1[:256] ; q = h @ Wm1[256:] + bm1   (BtS scratch lives in bE)
        small_gemm<false,false>(bH, Wm1,            nullptr, bP, bE, ATB, tid);
        small_gemm<false,true >(bH, Wm1 + NH * NH,  bm1,     bQ, bE, ATB, tid);
        __syncthreads();
        // e := h  (so edge epilogue accumulates straight to x = h + edges)
        {
            const int r = tid >> 4, c0 = (tid & 15) * 16;
#pragma unroll
            for (int v4 = 0; v4 < 4; ++v4)
                st4(bE + r * STR + c0 + v4 * 4, ld4(bH + r * STR + c0 + v4 * 4));
        }
        // ---- edge GEMM: 256 pairs x 256, in two 128-row chunks, 8x16 tiles ----
        const int rg = tid >> 4;   // 16 row-groups of 8 rows
        const int cg = tid & 15;   // 16 col-groups of 16 cols
        for (int ch = 0; ch < 2; ++ch) {
            float acc[8][16];
#pragma unroll
            for (int m = 0; m < 8; ++m)
#pragma unroll
                for (int c = 0; c < 16; ++c) acc[m][c] = 0.f;
            for (int step = 0; step < 32; ++step) {
                const int ks = step * 8;
                __syncthreads();
#pragma unroll
                for (int vi = 0; vi < 2; ++vi) {          // Wm2 rows ks..ks+7
                    int v = tid * 2 + vi;
                    int kt = v >> 6, c = (v & 63) * 4;
                    st4(BTB + kt * 256 + c, ld4(Wm2 + (ks + kt) * NH + c));
                }
#pragma unroll
                for (int fi = 0; fi < 4; ++fi) {          // A^T tile = relu(p_i + q_j)
                    int f = tid * 4 + fi;
                    int kt = f >> 7, row = f & 127;
                    int ii = ch * 8 + (row >> 4), jj = row & 15;
                    ATB[kt * 128 + row] =
                        fmaxf(bP[ii * STR + ks + kt] + bQ[jj * STR + ks + kt], 0.f);
                }
                __syncthreads();
#pragma unroll
                for (int kt = 0; kt < 8; ++kt) {
                    const float* ap = ATB + kt * 128 + rg * 8;
                    const float* bp = BTB + kt * 256 + cg * 16;
                    float4v a0 = ld4(ap), a1 = ld4(ap + 4);
                    float4v b0 = ld4(bp), b1 = ld4(bp + 4), b2 = ld4(bp + 8), b3 = ld4(bp + 12);
                    float a[8]  = {a0[0],a0[1],a0[2],a0[3],a1[0],a1[1],a1[2],a1[3]};
                    float b[16] = {b0[0],b0[1],b0[2],b0[3], b1[0],b1[1],b1[2],b1[3],
                                   b2[0],b2[1],b2[2],b2[3], b3[0],b3[1],b3[2],b3[3]};
#pragma unroll
                    for (int m = 0; m < 8; ++m)
#pragma unroll
                        for (int c = 0; c < 16; ++c)
                            acc[m][c] = fmaf(a[m], b[c], acc[m][c]);
                }
            }
            // epilogue: relu(acc + bm2), masked sum over j != i, accumulate into e
            const int iLoc  = ch * 8 + (rg >> 1);
            const int jBase = (rg & 1) * 8;
            const int cb    = cg * 16;
            float bm2r[16], part[16];
#pragma unroll
            for (int c = 0; c < 16; ++c) { bm2r[c] = bm2[cb + c]; part[c] = 0.f; }
#pragma unroll
            for (int m = 0; m < 8; ++m) {
                const float msk = (jBase + m == iLoc) ? 0.f : 1.f;
#pragma unroll
                for (int c = 0; c < 16; ++c)
                    part[c] += msk * fmaxf(acc[m][c] + bm2r[c], 0.f);
            }
#pragma unroll
            for (int c = 0; c < 16; ++c)
                atomicAdd(&bE[iLoc * STR + cb + c], part[c]);
        }
        // ---- node update: h' = relu(x@Wu1+bu1)@Wu2 + bu2 ----
        small_gemm<true, true>(bE, Wu1, bu1, bH, bP, ATB, tid);  // y -> old-h buffer
        small_gemm<false,true>(bH, Wu2, bu2, bP, bQ, ATB, tid);  // h' -> old-p buffer
        float* tswap = bH; bH = bP; bP = tswap;
    }

    // ---- output head ----
    small_gemm<true,true>(bH, Wo1, bo1, bQ, bP, ATB, tid);       // y2 -> bQ
    __syncthreads();
    {
        const int r = tid >> 4, u = tid & 15;
        float partial = 0.f;
#pragma unroll
        for (int t2 = 0; t2 < 16; ++t2)
            partial = fmaf(bQ[r * STR + u * 16 + t2], Wo2[u * 16 + t2], partial);
        partial += __shfl_xor(partial, 1);
        partial += __shfl_xor(partial, 2);
        partial += __shfl_xor(partial, 4);
        partial += __shfl_xor(partial, 8);
        if (u == 0) LG[r] = partial + bo2[0];
    }
    __syncthreads();
    if (tid == 0) {
        float pr = 1.f;
#pragma unroll
        for (int i = 0; i < 16; ++i)
            pr *= 1.f / (1.f + expf(-LG[i]));
        out[g] = pr;
    }
}

extern "C" void kernel_launch(void* const* d_in, const int* in_sizes, int n_in,
                              void* d_out, int out_size, void* d_ws, size_t ws_size,
                              hipStream_t stream)
{
    (void)in_sizes; (void)n_in; (void)out_size; (void)d_ws; (void)ws_size;
    fcgn_kernel<<<dim3(NGRAPH), dim3(256), 0, stream>>>(
        (const float*)d_in[0],  (const float*)d_in[1],  (const float*)d_in[2],
        (const float*)d_in[3],  (const float*)d_in[4],  (const float*)d_in[5],
        (const float*)d_in[6],  (const float*)d_in[7],  (const float*)d_in[8],
        (const float*)d_in[9],  (const float*)d_in[10], (const float*)d_in[11],
        (const float*)d_in[12], (const float*)d_in[13], (const float*)d_in[14],
        (const int*)d_in[15],   (float*)d_out);
}

// Round 3
// 1126.537 us; speedup vs baseline: 1.4119x; 1.4119x over previous
//
#include <hip/hip_runtime.h>

#define STR 264          // padded row stride (floats) for 16x256 feature buffers
#define NGRAPH 512

typedef float float4v __attribute__((ext_vector_type(4)));
typedef float float2v __attribute__((ext_vector_type(2)));

__device__ __forceinline__ float4v ld4(const float* p){ return *(const float4v*)p; }
__device__ __forceinline__ void st4(float* p, float4v v){ *(float4v*)p = v; }
__device__ __forceinline__ void st2(float* p, float2v v){ *(float2v*)p = v; }

// C[16][256] (LDS, stride STR) = act(A[16][256] @ Bg[256][256] + bias)
// split-K-4 across lane quads, 8x8 tiles; B read DIRECT from global (L2-hot,
// each element needed by only 2 threads); A^T double-buffered in LDS (AtSd: 2x320 fl).
template<bool RELU, bool HASBIAS>
__device__ __forceinline__ void small_gemm(const float* __restrict__ A,
                                           const float* __restrict__ Bg,
                                           const float* __restrict__ bias,
                                           float* __restrict__ C,
                                           float* __restrict__ AtSd,
                                           int tid)
{
    const int s  = tid & 3;           // K-slice (64 k each)
    const int cg = (tid >> 2) & 31;   // 8 cols each
    const int rg = tid >> 7;          // 8 rows each
    // staging mapping: lane -> (kt,ss,r); kt fastest => A column-read only ~4-way
    const int w_kt = tid & 3, w_ss = (tid >> 2) & 3, w_r = tid >> 4;
    const int wOff  = w_kt*80 + w_ss*20 + w_r;        // stride-20 pad: conflict-free reads
    const int rBase = w_r*STR + w_ss*64 + w_kt;

    __syncthreads();                  // protect A (written by previous phase)
    AtSd[wOff] = A[rBase];            // stage ks=0
    __syncthreads();

    float acc[8][8];
#pragma unroll
    for (int m=0;m<8;++m)
#pragma unroll
        for (int c=0;c<8;++c) acc[m][c]=0.f;

    for (int step = 0; step < 16; ++step) {
        const int ks = step*4;
        const float* cur = AtSd + (step&1)*320;
        float*       nxt = AtSd + ((step+1)&1)*320;
        if (step < 15) nxt[wOff] = A[rBase + ks + 4];
#pragma unroll
        for (int kt = 0; kt < 4; ++kt) {
            const float* ap = cur + kt*80 + s*20 + rg*8;
            const float* bp = Bg + (s*64 + ks + kt)*256 + cg*8;
            float4v a0 = ld4(ap), a1 = ld4(ap+4);
            float4v b0 = ld4(bp), b1 = ld4(bp+4);   // global (L2-resident weights)
            float a[8] = {a0[0],a0[1],a0[2],a0[3],a1[0],a1[1],a1[2],a1[3]};
            float b[8] = {b0[0],b0[1],b0[2],b0[3],b1[0],b1[1],b1[2],b1[3]};
#pragma unroll
            for (int m=0;m<8;++m)
#pragma unroll
                for (int c=0;c<8;++c) acc[m][c] = fmaf(a[m], b[c], acc[m][c]);
        }
        __syncthreads();
    }
    // reduce the 4 K-slices (quad lanes)
#pragma unroll
    for (int m=0;m<8;++m)
#pragma unroll
        for (int c=0;c<8;++c) {
            float v = acc[m][c];
            v += __shfl_xor(v,1);
            v += __shfl_xor(v,2);
            acc[m][c] = v;
        }
    if (s == 0) {
        const int c0 = cg*8;
#pragma unroll
        for (int m=0;m<8;++m) {
            const int r = rg*8+m;
            float o[8];
#pragma unroll
            for (int c=0;c<8;++c){
                float v = acc[m][c];
                if (HASBIAS) v += bias[c0+c];
                if (RELU)    v = fmaxf(v,0.f);
                o[c]=v;
            }
            st4(C + r*STR + c0,     (float4v){o[0],o[1],o[2],o[3]});
            st4(C + r*STR + c0 + 4, (float4v){o[4],o[5],o[6],o[7]});
        }
    }
    // NOTE: no trailing sync; every consumer phase begins with __syncthreads()
}

__global__ __launch_bounds__(256, 2)
void fcgn_kernel(const float* __restrict__ towers, const float* __restrict__ We,
                 const float* __restrict__ be,  const float* __restrict__ Wm1,
                 const float* __restrict__ bm1, const float* __restrict__ Wm2,
                 const float* __restrict__ bm2, const float* __restrict__ Wu1,
                 const float* __restrict__ bu1, const float* __restrict__ Wu2,
                 const float* __restrict__ bu2, const float* __restrict__ Wo1,
                 const float* __restrict__ bo1, const float* __restrict__ Wo2,
                 const float* __restrict__ bo2, const int* __restrict__ kPtr,
                 float* __restrict__ out)
{
    __shared__ alignas(16) float bH[16*STR];     // h, then x=h+edges, then h'
    __shared__ alignas(16) float bP[16*STR];     // p / y
    __shared__ alignas(16) float bQ[16*STR];     // q
    __shared__ alignas(16) float BTBd[2][8*256]; // edge Wm2 k-tile (XOR-swizzled 16B slots)
    __shared__ alignas(16) float ATBd[2][8*64];  // edge relu(p_i+q_j)^T tile (64 pair-rows)
    __shared__ alignas(16) float AtSd[2*320];    // small_gemm A^T tile
    __shared__ float TW[224];
    __shared__ float LG[16];

    const int gid = blockIdx.x;
    const int tid = threadIdx.x;

    if (tid < 224) TW[tid] = towers[gid*224 + tid];
    __syncthreads();

    // ---- encoder: h = towers @ We + be ----
    {
        const int r = tid >> 4, u = tid & 15;
        for (int cc = 0; cc < 16; ++cc) {
            const int c = cc*16 + u;
            float sum = be[c];
#pragma unroll
            for (int f = 0; f < 14; ++f)
                sum = fmaf(TW[r*14 + f], We[f*256 + c], sum);
            bH[r*STR + c] = sum;
        }
    }

    int kk = kPtr[0];
    if (kk < 0) kk = 0;
    if (kk > 8) kk = 8;   // defensive: garbage k must not hang the GPU

    // edge-phase thread mapping: 8x8 tile over 64 pair-rows x 256 cols, 4 chunks
    const int e_rg = tid >> 5;     // 8 rowgroups of 8 pair-rows
    const int e_cg = tid & 31;     // 32 colgroups of 8 cols
    const int sl0 = 2*e_cg, sl1 = 2*e_cg + 1;
    const int off0 = (sl0 ^ ((sl0>>3)&7))*4;     // XOR-swizzled 16B-slot offsets (floats)
    const int off1 = (sl1 ^ ((sl1>>3)&7))*4;
    const int iLoc0 = e_rg >> 1;                 // within-chunk sender index
    const int jBase = (e_rg & 1)*8;

    // staging lambdas (all 256 threads, uniform)
    auto stage_edge = [&](int buf, int ch_s, int ks_s) {
        // B: Wm2 rows [ks_s..ks_s+8) -> swizzled slots; coalesced 16B/lane
#pragma unroll
        for (int vi = 0; vi < 2; ++vi) {
            const int kt = (tid>>6) + vi*4;
            const int sl = tid & 63;
            const int phys = sl ^ ((sl>>3)&7);
            st4(&BTBd[buf][kt*256 + phys*4], ld4(Wm2 + (ks_s+kt)*256 + sl*4));
        }
        // A^T: 8 k-rows x 64 pair-rows of relu(p_i + q_j); st2 packed
        {
            const int kt = tid >> 5;
            const int r0 = (tid & 31)*2;
            const int ii = ch_s*4 + (r0 >> 4);
            const int j0 = r0 & 15;
            const int k0 = ks_s + kt;
            const float pv = bP[ii*STR + k0];
            const float v0 = fmaxf(pv + bQ[j0*STR + k0],     0.f);
            const float v1 = fmaxf(pv + bQ[(j0+1)*STR + k0], 0.f);
            st2(&ATBd[buf][kt*64 + r0], (float2v){v0, v1});
        }
    };

    for (int rnd = 0; rnd < kk; ++rnd) {
        // p = h @ Wm1[:256] ; q = h @ Wm1[256:] + bm1
        small_gemm<false,false>(bH, Wm1,           nullptr, bP, AtSd, tid);
        small_gemm<false,true >(bH, Wm1 + 256*256, bm1,     bQ, AtSd, tid);

        // ---- edge GEMM: 256 pair-rows x 256 cols, 4 chunks of 64 rows ----
        __syncthreads();              // q C-writes -> visible
        stage_edge(0, 0, 0);
        __syncthreads();

        float eacc[8][8];
#pragma unroll
        for (int m=0;m<8;++m)
#pragma unroll
            for (int c=0;c<8;++c) eacc[m][c]=0.f;

        for (int g = 0; g < 128; ++g) {
            const int ch = g >> 5, step = g & 31;
            const float* BT = BTBd[g & 1];
            const float* AT = ATBd[g & 1];
            if (g < 127) {
                const int gn = g + 1;
                stage_edge(gn & 1, gn >> 5, (gn & 31)*8);
            }
#pragma unroll
            for (int kt = 0; kt < 8; ++kt) {
                const float* ap = AT + kt*64 + e_rg*8;
                const float* bb = BT + kt*256;
                float4v a0 = ld4(ap), a1 = ld4(ap+4);
                float4v b0 = ld4(bb + off0), b1 = ld4(bb + off1);
                float a[8] = {a0[0],a0[1],a0[2],a0[3],a1[0],a1[1],a1[2],a1[3]};
                float b[8] = {b0[0],b0[1],b0[2],b0[3],b1[0],b1[1],b1[2],b1[3]};
#pragma unroll
                for (int m=0;m<8;++m)
#pragma unroll
                    for (int c=0;c<8;++c) eacc[m][c] = fmaf(a[m], b[c], eacc[m][c]);
            }
            if (step == 31) {
                // epilogue: relu(acc+bm2), mask j!=i, pair-reduce, += into bH (x = h+edges)
                const int iG = ch*4 + iLoc0;
                const int cb = e_cg*8;
                float part[8];
#pragma unroll
                for (int c=0;c<8;++c) part[c]=0.f;
#pragma unroll
                for (int m=0;m<8;++m) {
                    const float msk = (jBase + m == iG) ? 0.f : 1.f;
#pragma unroll
                    for (int c=0;c<8;++c)
                        part[c] += msk * fmaxf(eacc[m][c] + bm2[cb+c], 0.f);
                }
#pragma unroll
                for (int c=0;c<8;++c) part[c] += __shfl_xor(part[c], 32);
                if ((e_rg & 1) == 0) {           // single owner per (iG, col) -> plain RMW
                    float4v h0 = ld4(bH + iG*STR + cb);
                    float4v h1 = ld4(bH + iG*STR + cb + 4);
#pragma unroll
                    for (int c=0;c<4;++c){ h0[c]+=part[c]; h1[c]+=part[c+4]; }
                    st4(bH + iG*STR + cb,     h0);
                    st4(bH + iG*STR + cb + 4, h1);
                }
#pragma unroll
                for (int m=0;m<8;++m)
#pragma unroll
                    for (int c=0;c<8;++c) eacc[m][c]=0.f;
            }
            __syncthreads();
        }

        // ---- node update: h' = relu(x@Wu1+bu1)@Wu2 + bu2 ----
        small_gemm<true ,true>(bH, Wu1, bu1, bP, AtSd, tid);   // y  -> bP
        small_gemm<false,true>(bP, Wu2, bu2, bH, AtSd, tid);   // h' -> bH
    }

    // ---- output head ----
    small_gemm<true,true>(bH, Wo1, bo1, bP, AtSd, tid);        // y2 -> bP
    __syncthreads();
    {
        const int r = tid >> 4, u = tid & 15;
        float partial = 0.f;
#pragma unroll
        for (int t2 = 0; t2 < 16; ++t2)
            partial = fmaf(bP[r*STR + u*16 + t2], Wo2[u*16 + t2], partial);
        partial += __shfl_xor(partial, 1);
        partial += __shfl_xor(partial, 2);
        partial += __shfl_xor(partial, 4);
        partial += __shfl_xor(partial, 8);
        if (u == 0) LG[r] = partial + bo2[0];
    }
    __syncthreads();
    if (tid == 0) {
        float pr = 1.f;
#pragma unroll
        for (int i = 0; i < 16; ++i)
            pr *= 1.f / (1.f + expf(-LG[i]));
        out[gid] = pr;
    }
}

extern "C" void kernel_launch(void* const* d_in, const int* in_sizes, int n_in,
                              void* d_out, int out_size, void* d_ws, size_t ws_size,
                              hipStream_t stream)
{
    (void)in_sizes; (void)n_in; (void)out_size; (void)d_ws; (void)ws_size;
    fcgn_kernel<<<dim3(NGRAPH), dim3(256), 0, stream>>>(
        (const float*)d_in[0],  (const float*)d_in[1],  (const float*)d_in[2],
        (const float*)d_in[3],  (const float*)d_in[4],  (const float*)d_in[5],
        (const float*)d_in[6],  (const float*)d_in[7],  (const float*)d_in[8],
        (const float*)d_in[9],  (const float*)d_in[10], (const float*)d_in[11],
        (const float*)d_in[12], (const float*)d_in[13], (const float*)d_in[14],
        (const int*)d_in[15],   (float*)d_out);
}